// Round 6
// baseline (314.146 us; speedup 1.0000x reference)
//
#include <hip/hip_runtime.h>

// Shapes (fixed by the reference):
//   x:  (N=32, C=384, H=56, W=56)  -> (n, c, p) with HW=3136 = 98*32
//   gf: (N=32, M=8, D=768)
//   W_kv: (E=768, D=768)  (E = 2*C = 768 total rows), b_kv: (768,)
//   kv[n][m][e] = clip(sum_d gf[n][m][d]*W[e][d] + b[e], 0, 6)
//   K = kv[..., :384], V = kv[..., 384:]
//   scores[n,p,k] = sum_c x[n,c,p]*K[n,k,c]; attn = softmax_k
//   out[n,c,p] = x[n,c,p] + sum_k attn[n,p,k]*V[n,k,c]

#define NC 384
#define HWP 3136
#define DD 768
#define MM 8
#define EE 768

// ---------------- Kernel 1: KV projection + ReLU6 (unchanged r5) ----------------
// grid (48, 16), block 256 = 4 waves; block = (16 e-rows, 2 n's).
__global__ __launch_bounds__(256) void kv_kernel(const float* __restrict__ gf,
                                                 const float* __restrict__ Wk,
                                                 const float* __restrict__ bk,
                                                 float* __restrict__ kv) {
    __shared__ float g[MM * DD];  // 24 KB
    const int t = threadIdx.x;
    const int lane = t & 63;
    const int w = t >> 6;
    const int grp = lane >> 4;       // row within the wave's quad (0..3)
    const int lq = lane & 15;        // d-slice owner within the group
    const int e = blockIdx.x * 16 + w * 4 + grp;   // 0..767

    float4 wr[12];
    const float* wrow = Wk + (size_t)e * DD;
    #pragma unroll
    for (int j = 0; j < 12; ++j)
        wr[j] = *(const float4*)(wrow + j * 64 + lq * 4);
    const float bv = bk[e];

    #pragma unroll
    for (int ni = 0; ni < 2; ++ni) {
        const int n = blockIdx.y * 2 + ni;           // 0..31
        if (ni) __syncthreads();
        const float4* gfn = (const float4*)(gf + (size_t)n * (MM * DD));
        float4* g4 = (float4*)g;
        #pragma unroll
        for (int r = 0; r < 6; ++r) g4[t + r * 256] = gfn[t + r * 256];
        __syncthreads();

        float res = 0.f;
        #pragma unroll
        for (int m = 0; m < 8; ++m) {
            float acc = 0.f;
            #pragma unroll
            for (int j = 0; j < 12; ++j) {
                const float4 gg = *(const float4*)&g[m * DD + j * 64 + lq * 4];
                acc += wr[j].x * gg.x + wr[j].y * gg.y
                     + wr[j].z * gg.z + wr[j].w * gg.w;
            }
            acc += __shfl_xor(acc, 1, 64);
            acc += __shfl_xor(acc, 2, 64);
            acc += __shfl_xor(acc, 4, 64);
            acc += __shfl_xor(acc, 8, 64);
            if (lq == m) res = acc;
        }
        if (lq < 8)
            kv[(size_t)n * (MM * EE) + (size_t)lq * EE + e] =
                fminf(fmaxf(res + bv, 0.f), 6.f);
    }
}

// ---------------- Kernel 2: fused attention + residual ----------------
// Round-3 structure, occupancy doubled: block = 512 threads (8 waves),
// same 32 positions/block, channel groups split 16x24 -> 32x12.
//   p2 = t&15 (position pair, float2 -> 128B segments, unchanged)
//   gq = t>>4 (0..31), c0 = gq*12; xr = 12 float2 (~48 live VGPRs)
// LDS = 24 KB kvs + 8 KB sc = 32 KB -> 4 blocks/CU x 8 waves = 32 waves/CU
// (HW cap; was 20). __launch_bounds__(512,8) pins VGPR <= 64.
// K/V reads: 4 distinct float4 spans/wave at word-offsets {0,12,24,36} mod 32
// -> disjoint banks, conflict-free broadcast. sc exchange now over 8 waves.
__global__ __launch_bounds__(512, 8) void attn_kernel(const float* __restrict__ x,
                                                      const float* __restrict__ kv,
                                                      float* __restrict__ out) {
    __shared__ float kvs[6144];     // 24 KB: [half*3072 + k*384 + c]
    __shared__ float sc[8][8][32];  // 8 KB: per-wave partial scores [w][k][pos]

    const int n = blockIdx.y;
    const int tile = blockIdx.x;     // 0..97
    const int t = threadIdx.x;       // 0..511
    const int p2 = t & 15;           // position pair
    const int gq = t >> 4;           // channel group (0..31)
    const int w = t >> 6;            // wave (0..7)
    const int c0 = gq * 12;
    const int pos0 = tile * 32 + p2 * 2;

    // stage this n's K/V into dense [half][k][c] layout (pure float4 copy)
    const float4* kvn4 = (const float4*)(kv + (size_t)n * (MM * EE));
    float4* kvs4 = (float4*)kvs;
    #pragma unroll
    for (int r = 0; r < 3; ++r) {
        const int f = t + r * 512;        // float4 index 0..1535
        const int k = f / 192;
        const int e4 = f - k * 192;       // 0..191
        const int half = (e4 >= 96) ? 1 : 0;
        const int c4 = e4 - half * 96;    // 0..95
        kvs4[half * 768 + k * 96 + c4] = kvn4[f];
    }
    __syncthreads();
    __builtin_amdgcn_sched_barrier(0);  // keep x loads below the barrier

    // load my 12 channels x 2 positions of x (float2, 8B/lane, 128B segments)
    const float* xp = x + (size_t)n * NC * HWP + (size_t)c0 * HWP + pos0;
    float2 xr[12];
    #pragma unroll
    for (int i = 0; i < 12; ++i) xr[i] = *(const float2*)(xp + (size_t)i * HWP);

    // partial scores over my 12 channels (K as broadcast float4 LDS reads)
    float accx[8], accy[8];
    #pragma unroll
    for (int k = 0; k < 8; ++k) { accx[k] = 0.f; accy[k] = 0.f; }

    const float* kbase = &kvs[gq * 12];
    #pragma unroll
    for (int i4 = 0; i4 < 3; ++i4) {
        const float2 x0 = xr[i4 * 4 + 0];
        const float2 x1 = xr[i4 * 4 + 1];
        const float2 x2 = xr[i4 * 4 + 2];
        const float2 x3 = xr[i4 * 4 + 3];
        #pragma unroll
        for (int k = 0; k < 8; ++k) {
            const float4 kk = *(const float4*)&kbase[k * 384 + i4 * 4];
            accx[k] += x0.x * kk.x + x1.x * kk.y + x2.x * kk.z + x3.x * kk.w;
            accy[k] += x0.y * kk.x + x1.y * kk.y + x2.y * kk.z + x3.y * kk.w;
        }
    }

    // in-wave reduce across the wave's 4 channel groups (lane bits 4,5)
    #pragma unroll
    for (int k = 0; k < 8; ++k) {
        accx[k] += __shfl_xor(accx[k], 16, 64);
        accx[k] += __shfl_xor(accx[k], 32, 64);
        accy[k] += __shfl_xor(accy[k], 16, 64);
        accy[k] += __shfl_xor(accy[k], 32, 64);
    }
    if ((t & 48) == 0) {  // lanes 0..15 of each wave hold the wave-partials
        #pragma unroll
        for (int k = 0; k < 8; ++k)
            *(float2*)&sc[w][k][p2 * 2] = make_float2(accx[k], accy[k]);
    }
    __syncthreads();

    // every thread: sum the 8 wave-partials for its 2 positions, softmax over k
    float sx[8], sy[8];
    #pragma unroll
    for (int k = 0; k < 8; ++k) {
        float2 s = *(const float2*)&sc[0][k][p2 * 2];
        #pragma unroll
        for (int ww = 1; ww < 8; ++ww) {
            const float2 q = *(const float2*)&sc[ww][k][p2 * 2];
            s.x += q.x; s.y += q.y;
        }
        sx[k] = s.x; sy[k] = s.y;
    }
    {
        float mx = sx[0], my = sy[0];
        #pragma unroll
        for (int k = 1; k < 8; ++k) { mx = fmaxf(mx, sx[k]); my = fmaxf(my, sy[k]); }
        float sux = 0.f, suy = 0.f;
        #pragma unroll
        for (int k = 0; k < 8; ++k) {
            sx[k] = __expf(sx[k] - mx); sux += sx[k];
            sy[k] = __expf(sy[k] - my); suy += sy[k];
        }
        const float ix = 1.f / sux, iy = 1.f / suy;
        #pragma unroll
        for (int k = 0; k < 8; ++k) { sx[k] *= ix; sy[k] *= iy; }
    }

    // epilogue: out = x + sum_k aw[k]*V[k][c]; xr is live, no x re-read
    float* op = out + (size_t)n * NC * HWP + (size_t)c0 * HWP + pos0;
    const float* vbase = &kvs[3072 + gq * 12];
    #pragma unroll
    for (int i4 = 0; i4 < 3; ++i4) {
        float2 o0 = xr[i4 * 4 + 0];
        float2 o1 = xr[i4 * 4 + 1];
        float2 o2 = xr[i4 * 4 + 2];
        float2 o3 = xr[i4 * 4 + 3];
        #pragma unroll
        for (int k = 0; k < 8; ++k) {
            const float4 vv = *(const float4*)&vbase[k * 384 + i4 * 4];
            o0.x += sx[k] * vv.x; o0.y += sy[k] * vv.x;
            o1.x += sx[k] * vv.y; o1.y += sy[k] * vv.y;
            o2.x += sx[k] * vv.z; o2.y += sy[k] * vv.z;
            o3.x += sx[k] * vv.w; o3.y += sy[k] * vv.w;
        }
        *(float2*)(op + (size_t)(i4 * 4 + 0) * HWP) = o0;
        *(float2*)(op + (size_t)(i4 * 4 + 1) * HWP) = o1;
        *(float2*)(op + (size_t)(i4 * 4 + 2) * HWP) = o2;
        *(float2*)(op + (size_t)(i4 * 4 + 3) * HWP) = o3;
    }
}

extern "C" void kernel_launch(void* const* d_in, const int* in_sizes, int n_in,
                              void* d_out, int out_size, void* d_ws, size_t ws_size,
                              hipStream_t stream) {
    const float* x  = (const float*)d_in[0];
    const float* gf = (const float*)d_in[1];
    const float* Wk = (const float*)d_in[2];
    const float* bk = (const float*)d_in[3];
    float* out = (float*)d_out;
    float* kv = (float*)d_ws;  // 32*8*768 floats = 768 KB

    kv_kernel<<<dim3(48, 16), 256, 0, stream>>>(gf, Wk, bk, kv);
    attn_kernel<<<dim3(98, 32), 512, 0, stream>>>(x, kv, out);
}